// Round 2
// baseline (826.267 us; speedup 1.0000x reference)
//
#include <hip/hip_runtime.h>
#include <hip/hip_bf16.h>

// GQA: B=2, T=2048, EMB=2048, H=16, G=4, GS=4, HD=128, causal, eval-mode dropout.
// Pipeline: cast(bf16) -> Q/K/V projections (K,V compacted to 512 ch; V emitted
// transposed) -> flash attention (MFMA 16x16x32) -> out proj + bias (f32 out).

typedef unsigned short ushort_t;
typedef __bf16 bf16x8 __attribute__((ext_vector_type(8)));
typedef float f32x4 __attribute__((ext_vector_type(4)));

__device__ __forceinline__ ushort_t f2bf(float f) {
  union { float f; unsigned u; } x; x.f = f;
  unsigned r = x.u + 0x7fffu + ((x.u >> 16) & 1u);
  return (ushort_t)(r >> 16);
}

// ---------------- casts ----------------
__global__ __launch_bounds__(256) void cast4(const float* __restrict__ in,
                                             ushort_t* __restrict__ out) {
  int i = blockIdx.x * 256 + threadIdx.x;
  float4 v = reinterpret_cast<const float4*>(in)[i];
  ushort4 o;
  o.x = f2bf(v.x); o.y = f2bf(v.y); o.z = f2bf(v.z); o.w = f2bf(v.w);
  reinterpret_cast<ushort4*>(out)[i] = o;
}

// Wk/Wv: keep only rows g*512+d (d<128) -> compact 512x2048, row n = g*128+d.
__global__ __launch_bounds__(256) void cast_compact(const float* __restrict__ in,
                                                    ushort_t* __restrict__ out) {
  int i = blockIdx.x * 256 + threadIdx.x;   // 512 rows * 512 float4 chunks
  int row = i >> 9, c = i & 511;
  int srow = ((row >> 7) << 9) | (row & 127);
  float4 v = reinterpret_cast<const float4*>(in + (size_t)srow * 2048)[c];
  ushort4 o;
  o.x = f2bf(v.x); o.y = f2bf(v.y); o.z = f2bf(v.z); o.w = f2bf(v.w);
  reinterpret_cast<ushort4*>(out + (size_t)row * 2048)[c] = o;
}

// ---------------- GEMM: C[M,N] = A[M,K] * B[N,K]^T (both row-major, K-contig) ----
// 128x128 tile, BK=32, 4 waves (2x2 of 64x64), global_load_lds width-16 staging.
template<bool FINAL>
__global__ __launch_bounds__(256) void gemm_bt(const ushort_t* __restrict__ A,
                                               const ushort_t* __restrict__ B,
                                               ushort_t* __restrict__ Cb,
                                               float* __restrict__ Cf,
                                               const float* __restrict__ bias,
                                               int M, int N, int K) {
  __shared__ ushort_t lA[128 * 32];
  __shared__ ushort_t lB[128 * 32];
  const int lane = threadIdx.x & 63;
  const int w = threadIdx.x >> 6;
  const int m0 = blockIdx.y * 128;
  const int n0 = blockIdx.x * 128;
  const int wm = (w >> 1) * 64, wn = (w & 1) * 64;
  const int l4 = lane >> 4, l15 = lane & 15;

  const f32x4 zero = {0.f, 0.f, 0.f, 0.f};
  f32x4 acc[4][4];
#pragma unroll
  for (int i = 0; i < 4; ++i)
#pragma unroll
    for (int j = 0; j < 4; ++j) acc[i][j] = zero;

  const int srow = w * 16 + (lane >> 2);   // staging row within tile (per issue)
  const int scol = (lane & 3) * 8;         // staging col (elements)
  const ushort_t* ga = A + (size_t)(m0 + srow) * K + scol;
  const ushort_t* gb = B + (size_t)(n0 + srow) * K + scol;

  for (int kt = 0; kt < K; kt += 32) {
#pragma unroll
    for (int i = 0; i < 2; ++i) {
      __builtin_amdgcn_global_load_lds(
          (const __attribute__((address_space(1))) void*)(ga + (size_t)i * 64 * K + kt),
          (__attribute__((address_space(3))) void*)(&lA[w * 512 + i * 2048]), 16, 0, 0);
      __builtin_amdgcn_global_load_lds(
          (const __attribute__((address_space(1))) void*)(gb + (size_t)i * 64 * K + kt),
          (__attribute__((address_space(3))) void*)(&lB[w * 512 + i * 2048]), 16, 0, 0);
    }
    __syncthreads();  // drains vmcnt + barrier
    bf16x8 af[4], bfr[4];
#pragma unroll
    for (int t = 0; t < 4; ++t) {
      af[t]  = *reinterpret_cast<const bf16x8*>(&lA[(wm + t * 16 + l15) * 32 + l4 * 8]);
      bfr[t] = *reinterpret_cast<const bf16x8*>(&lB[(wn + t * 16 + l15) * 32 + l4 * 8]);
    }
#pragma unroll
    for (int mi = 0; mi < 4; ++mi)
#pragma unroll
      for (int ni = 0; ni < 4; ++ni)
        acc[mi][ni] = __builtin_amdgcn_mfma_f32_16x16x32_bf16(af[mi], bfr[ni],
                                                              acc[mi][ni], 0, 0, 0);
    __syncthreads();
  }

#pragma unroll
  for (int mi = 0; mi < 4; ++mi)
#pragma unroll
    for (int ni = 0; ni < 4; ++ni) {
      int row = m0 + wm + mi * 16 + l4 * 4;
      int col = n0 + wn + ni * 16 + l15;
#pragma unroll
      for (int r = 0; r < 4; ++r) {
        float v = acc[mi][ni][r];
        if (FINAL) Cf[(size_t)(row + r) * N + col] = v + bias[col];
        else       Cb[(size_t)(row + r) * N + col] = f2bf(v);
      }
    }
}

// ---------------- flash attention ----------------
// Block = 4 independent waves; wave owns 16 q-rows of one (b,hq); KV tile = 64.
// Q (bf16) in regs; K [4096,512] and V^T [512,4096] fragments straight from L2.
__global__ __launch_bounds__(256) void attn_kernel(const ushort_t* __restrict__ Qb,
                                                   const ushort_t* __restrict__ Kb,
                                                   const ushort_t* __restrict__ Vt,
                                                   ushort_t* __restrict__ Ob) {
  __shared__ ushort_t pbuf[4][16 * 72];  // per-wave P tile, padded rows (144B, 16B-aligned)
  const int lane = threadIdx.x & 63;
  const int w = threadIdx.x >> 6;
  const int bid = blockIdx.x;             // (b, hq, qt)
  const int b = bid >> 9, hq = (bid >> 5) & 15, qt = bid & 31;
  const int g = hq >> 2;
  const int q0 = qt * 64 + w * 16;
  const int l4 = lane >> 4, l15 = lane & 15;
  const float sc = 0.08838834764831845f;      // 1/sqrt(128)
  const float LOG2E = 1.4426950408889634f;

  bf16x8 qf[4];
  {
    const ushort_t* qp = Qb + (size_t)(b * 2048 + q0 + l15) * 2048 + hq * 128 + l4 * 8;
#pragma unroll
    for (int kk = 0; kk < 4; ++kk) qf[kk] = *reinterpret_cast<const bf16x8*>(qp + kk * 32);
  }

  const f32x4 zero = {0.f, 0.f, 0.f, 0.f};
  f32x4 o[8];
#pragma unroll
  for (int i = 0; i < 8; ++i) o[i] = zero;
  float mr[4] = {-3.0e38f, -3.0e38f, -3.0e38f, -3.0e38f};
  float lr[4] = {0.f, 0.f, 0.f, 0.f};

  const int qmax = q0 + 15;
  for (int j0 = 0; j0 <= qmax; j0 += 64) {
    // ---- S = Q K^T (16 x 64) ----
    f32x4 s[4];
#pragma unroll
    for (int i = 0; i < 4; ++i) s[i] = zero;
    const ushort_t* kp = Kb + (size_t)(b * 2048 + j0 + l15) * 512 + g * 128 + l4 * 8;
#pragma unroll
    for (int ni = 0; ni < 4; ++ni)
#pragma unroll
      for (int kk = 0; kk < 4; ++kk) {
        bf16x8 kf = *reinterpret_cast<const bf16x8*>(kp + ni * (16 * 512) + kk * 32);
        s[ni] = __builtin_amdgcn_mfma_f32_16x16x32_bf16(qf[kk], kf, s[ni], 0, 0, 0);
      }
    // ---- scale + causal mask + row max (rows live at (l4*4+r), cols at l15) ----
    float pv[4][4];
    float pmax[4] = {-3.0e38f, -3.0e38f, -3.0e38f, -3.0e38f};
#pragma unroll
    for (int ni = 0; ni < 4; ++ni) {
      int col = j0 + ni * 16 + l15;
#pragma unroll
      for (int r = 0; r < 4; ++r) {
        int qq = q0 + l4 * 4 + r;
        float v = (col <= qq) ? s[ni][r] * sc : -3.0e38f;
        pv[ni][r] = v;
        pmax[r] = fmaxf(pmax[r], v);
      }
    }
#pragma unroll
    for (int r = 0; r < 4; ++r) {
#pragma unroll
      for (int d = 1; d < 16; d <<= 1) pmax[r] = fmaxf(pmax[r], __shfl_xor(pmax[r], d, 16));
      float mn = fmaxf(mr[r], pmax[r]);
      float corr = exp2f((mr[r] - mn) * LOG2E);
      mr[r] = mn;
      lr[r] *= corr;
#pragma unroll
      for (int i = 0; i < 8; ++i) o[i][r] *= corr;
    }
    // ---- P = exp(S-m), partial row-sums, reshape via LDS to A-fragments ----
#pragma unroll
    for (int ni = 0; ni < 4; ++ni)
#pragma unroll
      for (int r = 0; r < 4; ++r) {
        float p = exp2f((pv[ni][r] - mr[r]) * LOG2E);
        lr[r] += p;
        pbuf[w][(l4 * 4 + r) * 72 + ni * 16 + l15] = f2bf(p);
      }
    bf16x8 pa[2];
#pragma unroll
    for (int kk2 = 0; kk2 < 2; ++kk2)
      pa[kk2] = *reinterpret_cast<const bf16x8*>(&pbuf[w][l15 * 72 + kk2 * 32 + l4 * 8]);
    // ---- O += P V  (V^T layout: [g*128+d][4096], k-contiguous) ----
    const ushort_t* vp = Vt + (size_t)(g * 128 + l15) * 4096 + b * 2048 + j0 + l4 * 8;
#pragma unroll
    for (int ni = 0; ni < 8; ++ni)
#pragma unroll
      for (int kk2 = 0; kk2 < 2; ++kk2) {
        bf16x8 vf = *reinterpret_cast<const bf16x8*>(vp + ni * (16 * 4096) + kk2 * 32);
        o[ni] = __builtin_amdgcn_mfma_f32_16x16x32_bf16(pa[kk2], vf, o[ni], 0, 0, 0);
      }
  }
  // ---- finalize: row-sum reduce, divide, store ----
#pragma unroll
  for (int r = 0; r < 4; ++r)
#pragma unroll
    for (int d = 1; d < 16; d <<= 1) lr[r] += __shfl_xor(lr[r], d, 16);
  ushort_t* op = Ob + (size_t)(b * 2048 + q0) * 2048 + hq * 128;
#pragma unroll
  for (int ni = 0; ni < 8; ++ni)
#pragma unroll
    for (int r = 0; r < 4; ++r)
      op[(size_t)(l4 * 4 + r) * 2048 + ni * 16 + l15] = f2bf(o[ni][r] / lr[r]);
}

// ---------------- launch ----------------
extern "C" void kernel_launch(void* const* d_in, const int* in_sizes, int n_in,
                              void* d_out, int out_size, void* d_ws, size_t ws_size,
                              hipStream_t stream) {
  const float* x  = (const float*)d_in[0];
  const float* Wq = (const float*)d_in[1];
  const float* Wk = (const float*)d_in[2];
  const float* Wv = (const float*)d_in[3];
  const float* Wp = (const float*)d_in[4];
  const float* bp = (const float*)d_in[5];
  float* out = (float*)d_out;

  char* ws = (char*)d_ws;
  size_t off = 0;
  ushort_t* xb   = (ushort_t*)(ws + off); off += (size_t)4096 * 2048 * 2;
  ushort_t* wqb  = (ushort_t*)(ws + off); off += (size_t)2048 * 2048 * 2;
  ushort_t* wkb  = (ushort_t*)(ws + off); off += (size_t)512 * 2048 * 2;
  ushort_t* wvb  = (ushort_t*)(ws + off); off += (size_t)512 * 2048 * 2;
  ushort_t* wpb  = (ushort_t*)(ws + off); off += (size_t)2048 * 2048 * 2;
  ushort_t* qbuf = (ushort_t*)(ws + off); off += (size_t)4096 * 2048 * 2;
  ushort_t* kbuf = (ushort_t*)(ws + off); off += (size_t)4096 * 512 * 2;
  ushort_t* vtb  = (ushort_t*)(ws + off); off += (size_t)512 * 4096 * 2;
  ushort_t* obuf = (ushort_t*)(ws + off); off += (size_t)4096 * 2048 * 2;

  cast4<<<8192, 256, 0, stream>>>(x, xb);            // 4096x2048
  cast4<<<4096, 256, 0, stream>>>(Wq, wqb);          // 2048x2048
  cast4<<<4096, 256, 0, stream>>>(Wp, wpb);
  cast_compact<<<1024, 256, 0, stream>>>(Wk, wkb);   // 512x2048
  cast_compact<<<1024, 256, 0, stream>>>(Wv, wvb);

  // Q = x Wq^T            (4096 x 2048)
  gemm_bt<false><<<dim3(16, 32), 256, 0, stream>>>(xb, wqb, qbuf, nullptr, nullptr,
                                                   4096, 2048, 2048);
  // K = x Wk_c^T          (4096 x 512)
  gemm_bt<false><<<dim3(4, 32), 256, 0, stream>>>(xb, wkb, kbuf, nullptr, nullptr,
                                                  4096, 512, 2048);
  // V^T = Wv_c x^T        (512 x 4096)  -- operands swapped to emit transposed V
  gemm_bt<false><<<dim3(32, 4), 256, 0, stream>>>(wvb, xb, vtb, nullptr, nullptr,
                                                  512, 4096, 2048);

  attn_kernel<<<1024, 256, 0, stream>>>(qbuf, kbuf, vtb, obuf);

  // out = O Wp^T + bp     (4096 x 2048, f32)
  gemm_bt<true><<<dim3(16, 32), 256, 0, stream>>>(obuf, wpb, nullptr, out, bp,
                                                  4096, 2048, 2048);
}

// Round 4
// 445.319 us; speedup vs baseline: 1.8554x; 1.8554x over previous
//
#include <hip/hip_runtime.h>
#include <hip/hip_bf16.h>

// GQA: B=2, T=2048, EMB=2048, H=16, G=4, GS=4, HD=128, causal, eval-mode dropout.
// Pipeline: cast(bf16) -> fused QK projection + V^T projection -> flash attention
// (LDS-staged K/V shared by 4 waves, XOR-swizzled) -> out proj + bias (f32 out).

typedef unsigned short ushort_t;
typedef __bf16 bf16x8 __attribute__((ext_vector_type(8)));
typedef float f32x4 __attribute__((ext_vector_type(4)));

__device__ __forceinline__ ushort_t f2bf(float f) {
  union { float f; unsigned u; } x; x.f = f;
  unsigned r = x.u + 0x7fffu + ((x.u >> 16) & 1u);
  return (ushort_t)(r >> 16);
}

// ---------------- casts ----------------
__global__ __launch_bounds__(256) void cast4(const float* __restrict__ in,
                                             ushort_t* __restrict__ out) {
  int i = blockIdx.x * 256 + threadIdx.x;
  float4 v = reinterpret_cast<const float4*>(in)[i];
  ushort4 o;
  o.x = f2bf(v.x); o.y = f2bf(v.y); o.z = f2bf(v.z); o.w = f2bf(v.w);
  reinterpret_cast<ushort4*>(out)[i] = o;
}

// Wk/Wv: keep only rows g*512+d (d<128) -> compact 512x2048, row n = g*128+d.
__global__ __launch_bounds__(256) void cast_compact(const float* __restrict__ in,
                                                    ushort_t* __restrict__ out) {
  int i = blockIdx.x * 256 + threadIdx.x;   // 512 rows * 512 float4 chunks
  int row = i >> 9, c = i & 511;
  int srow = ((row >> 7) << 9) | (row & 127);
  float4 v = reinterpret_cast<const float4*>(in + (size_t)srow * 2048)[c];
  ushort4 o;
  o.x = f2bf(v.x); o.y = f2bf(v.y); o.z = f2bf(v.z); o.w = f2bf(v.w);
  reinterpret_cast<ushort4*>(out + (size_t)row * 2048)[c] = o;
}

// ---------------- GEMM: C[M,N] = A[M,K] * B[N,K]^T (both row-major, K-contig) ----
// 128x128 tile, BK=32, 4 waves (2x2 of 64x64), global_load_lds width-16 staging.
template<bool FINAL>
__global__ __launch_bounds__(256) void gemm_bt(const ushort_t* __restrict__ A,
                                               const ushort_t* __restrict__ B,
                                               ushort_t* __restrict__ Cb,
                                               float* __restrict__ Cf,
                                               const float* __restrict__ bias,
                                               int M, int N, int K) {
  __shared__ ushort_t lA[128 * 32];
  __shared__ ushort_t lB[128 * 32];
  const int lane = threadIdx.x & 63;
  const int w = threadIdx.x >> 6;
  const int m0 = blockIdx.y * 128;
  const int n0 = blockIdx.x * 128;
  const int wm = (w >> 1) * 64, wn = (w & 1) * 64;
  const int l4 = lane >> 4, l15 = lane & 15;

  const f32x4 zero = {0.f, 0.f, 0.f, 0.f};
  f32x4 acc[4][4];
#pragma unroll
  for (int i = 0; i < 4; ++i)
#pragma unroll
    for (int j = 0; j < 4; ++j) acc[i][j] = zero;

  const int srow = w * 16 + (lane >> 2);   // staging row within tile (per issue)
  const int scol = (lane & 3) * 8;         // staging col (elements)
  const ushort_t* ga = A + (size_t)(m0 + srow) * K + scol;
  const ushort_t* gb = B + (size_t)(n0 + srow) * K + scol;

  for (int kt = 0; kt < K; kt += 32) {
#pragma unroll
    for (int i = 0; i < 2; ++i) {
      __builtin_amdgcn_global_load_lds(
          (const __attribute__((address_space(1))) void*)(ga + (size_t)i * 64 * K + kt),
          (__attribute__((address_space(3))) void*)(&lA[w * 512 + i * 2048]), 16, 0, 0);
      __builtin_amdgcn_global_load_lds(
          (const __attribute__((address_space(1))) void*)(gb + (size_t)i * 64 * K + kt),
          (__attribute__((address_space(3))) void*)(&lB[w * 512 + i * 2048]), 16, 0, 0);
    }
    __syncthreads();  // drains vmcnt + barrier
    bf16x8 af[4], bfr[4];
#pragma unroll
    for (int t = 0; t < 4; ++t) {
      af[t]  = *reinterpret_cast<const bf16x8*>(&lA[(wm + t * 16 + l15) * 32 + l4 * 8]);
      bfr[t] = *reinterpret_cast<const bf16x8*>(&lB[(wn + t * 16 + l15) * 32 + l4 * 8]);
    }
#pragma unroll
    for (int mi = 0; mi < 4; ++mi)
#pragma unroll
      for (int ni = 0; ni < 4; ++ni)
        acc[mi][ni] = __builtin_amdgcn_mfma_f32_16x16x32_bf16(af[mi], bfr[ni],
                                                              acc[mi][ni], 0, 0, 0);
    __syncthreads();
  }

#pragma unroll
  for (int mi = 0; mi < 4; ++mi)
#pragma unroll
    for (int ni = 0; ni < 4; ++ni) {
      int row = m0 + wm + mi * 16 + l4 * 4;
      int col = n0 + wn + ni * 16 + l15;
#pragma unroll
      for (int r = 0; r < 4; ++r) {
        float v = acc[mi][ni][r];
        if (FINAL) Cf[(size_t)(row + r) * N + col] = v + bias[col];
        else       Cb[(size_t)(row + r) * N + col] = f2bf(v);
      }
    }
}

// ---------------- flash attention v2 ----------------
// Block = 4 waves x 32 q-rows = 128 q-rows of one (b,hq). KV tile = 64, staged in
// LDS (shared across waves) via global_load_lds with pre-swizzled source; reads
// XOR-swizzled (chunk ^= row&7) to kill the 16-way row-stride bank conflict.
// Grid 512 = (b,hq,qb) with chunked XCD swizzle: one (b,g) per XCD -> K/V L2-fit.
__global__ __launch_bounds__(256, 2) void attn_kernel(const ushort_t* __restrict__ Qb, int ldQ,
                                                      const ushort_t* __restrict__ Kb, int ldK,
                                                      const ushort_t* __restrict__ Vt,
                                                      ushort_t* __restrict__ Ob) {
  __shared__ ushort_t ldsK[64 * 128];   // row r: chunk c (16B) at slot c^(r&7)
  __shared__ ushort_t ldsV[128 * 64];   // row d: chunk c at slot c^(d&7)
  __shared__ ushort_t pbuf[4][32 * 72]; // per-wave P tile, padded rows (144B)

  const int lane = threadIdx.x & 63;
  const int w = threadIdx.x >> 6;
  const int swz = ((blockIdx.x & 7) << 6) | (blockIdx.x >> 3);  // chunked XCD swizzle
  const int b = swz >> 8, hq = (swz >> 4) & 15, qb = swz & 15;
  const int g = hq >> 2;
  const int q0w = qb * 128 + w * 32;
  const int l4 = lane >> 4, l15 = lane & 15;
  const float sc = 0.08838834764831845f;      // 1/sqrt(128)
  const float LOG2E = 1.4426950408889634f;

  // Q fragments (2 M-frags x K=128)
  bf16x8 qf[2][4];
#pragma unroll
  for (int m = 0; m < 2; ++m) {
    const ushort_t* qp = Qb + (size_t)(b * 2048 + q0w + 16 * m + l15) * ldQ + hq * 128 + l4 * 8;
#pragma unroll
    for (int kk = 0; kk < 4; ++kk) qf[m][kk] = *reinterpret_cast<const bf16x8*>(qp + kk * 32);
  }

  // staging source pointers (pre-swizzled columns; row&7 invariant across i)
  const int krow = w * 4 + (lane >> 4);                 // + i*16
  const ushort_t* kSrc = Kb + (size_t)(b * 2048 + krow) * ldK + g * 128 + (l15 ^ (krow & 7)) * 8;
  const int vrow = w * 8 + (lane >> 3);                 // + i*32
  const ushort_t* vSrc = Vt + (size_t)(g * 128 + vrow) * 4096 + b * 2048 + ((lane & 7) ^ (vrow & 7)) * 8;

  const f32x4 zero = {0.f, 0.f, 0.f, 0.f};
  f32x4 o[2][8];
#pragma unroll
  for (int m = 0; m < 2; ++m)
#pragma unroll
    for (int i = 0; i < 8; ++i) o[m][i] = zero;
  float mr[2][4], lr[2][4];
#pragma unroll
  for (int m = 0; m < 2; ++m)
#pragma unroll
    for (int r = 0; r < 4; ++r) { mr[m][r] = -3.0e38f; lr[m][r] = 0.f; }

  const int wqmax = q0w + 31;
  const int iters = 2 * qb + 2;
  for (int it = 0; it < iters; ++it) {
    const int j0 = it * 64;
    // ---- stage K (64x128) and V^T (128x64) tiles into LDS ----
#pragma unroll
    for (int i = 0; i < 4; ++i) {
      __builtin_amdgcn_global_load_lds(
          (const __attribute__((address_space(1))) void*)(kSrc + (size_t)i * 16 * ldK),
          (__attribute__((address_space(3))) void*)(&ldsK[i * 2048 + w * 512]), 16, 0, 0);
      __builtin_amdgcn_global_load_lds(
          (const __attribute__((address_space(1))) void*)(vSrc + (size_t)i * 32 * 4096),
          (__attribute__((address_space(3))) void*)(&ldsV[i * 2048 + w * 512]), 16, 0, 0);
    }
    kSrc += (size_t)64 * ldK;
    vSrc += 64;
    __syncthreads();   // drains vmcnt, LDS tiles ready

    if (j0 <= wqmax) {
      // ---- S = Q K^T (32 x 64) ----
      f32x4 s[2][4];
#pragma unroll
      for (int m = 0; m < 2; ++m)
#pragma unroll
        for (int i = 0; i < 4; ++i) s[m][i] = zero;
#pragma unroll
      for (int ni = 0; ni < 4; ++ni) {
        const int R = ni * 16 + l15;
#pragma unroll
        for (int kk = 0; kk < 4; ++kk) {
          bf16x8 kf = *reinterpret_cast<const bf16x8*>(
              &ldsK[R * 128 + ((kk * 4 + l4) ^ (R & 7)) * 8]);
          s[0][ni] = __builtin_amdgcn_mfma_f32_16x16x32_bf16(qf[0][kk], kf, s[0][ni], 0, 0, 0);
          s[1][ni] = __builtin_amdgcn_mfma_f32_16x16x32_bf16(qf[1][kk], kf, s[1][ni], 0, 0, 0);
        }
      }
      // ---- softmax per M-fragment ----
#pragma unroll
      for (int m = 0; m < 2; ++m) {
        float pv[4][4];
        float pmax[4] = {-3.0e38f, -3.0e38f, -3.0e38f, -3.0e38f};
#pragma unroll
        for (int ni = 0; ni < 4; ++ni) {
          int col = j0 + ni * 16 + l15;
#pragma unroll
          for (int r = 0; r < 4; ++r) {
            int qq = q0w + 16 * m + l4 * 4 + r;
            float v = (col <= qq) ? s[m][ni][r] * sc : -3.0e38f;
            pv[ni][r] = v;
            pmax[r] = fmaxf(pmax[r], v);
          }
        }
#pragma unroll
        for (int r = 0; r < 4; ++r) {
#pragma unroll
          for (int d = 1; d < 16; d <<= 1) pmax[r] = fmaxf(pmax[r], __shfl_xor(pmax[r], d, 16));
          float mn = fmaxf(mr[m][r], pmax[r]);
          float corr = exp2f((mr[m][r] - mn) * LOG2E);
          mr[m][r] = mn;
          lr[m][r] *= corr;
#pragma unroll
          for (int i = 0; i < 8; ++i) o[m][i][r] *= corr;
        }
#pragma unroll
        for (int ni = 0; ni < 4; ++ni)
#pragma unroll
          for (int r = 0; r < 4; ++r) {
            float p = exp2f((pv[ni][r] - mr[m][r]) * LOG2E);
            lr[m][r] += p;
            pbuf[w][(16 * m + l4 * 4 + r) * 72 + ni * 16 + l15] = f2bf(p);
          }
      }
      // ---- P fragments, O += P V ----
      bf16x8 pa0[2], pa1[2];
#pragma unroll
      for (int kk2 = 0; kk2 < 2; ++kk2) {
        pa0[kk2] = *reinterpret_cast<const bf16x8*>(&pbuf[w][(l15) * 72 + kk2 * 32 + l4 * 8]);
        pa1[kk2] = *reinterpret_cast<const bf16x8*>(&pbuf[w][(16 + l15) * 72 + kk2 * 32 + l4 * 8]);
      }
#pragma unroll
      for (int ni = 0; ni < 8; ++ni) {
        const int R = ni * 16 + l15;
#pragma unroll
        for (int kk2 = 0; kk2 < 2; ++kk2) {
          bf16x8 vf = *reinterpret_cast<const bf16x8*>(
              &ldsV[R * 64 + ((kk2 * 4 + l4) ^ (R & 7)) * 8]);
          o[0][ni] = __builtin_amdgcn_mfma_f32_16x16x32_bf16(pa0[kk2], vf, o[0][ni], 0, 0, 0);
          o[1][ni] = __builtin_amdgcn_mfma_f32_16x16x32_bf16(pa1[kk2], vf, o[1][ni], 0, 0, 0);
        }
      }
    }
    __syncthreads();   // LDS tiles free to overwrite
  }

  // ---- finalize: row-sum reduce, divide, store ----
#pragma unroll
  for (int m = 0; m < 2; ++m) {
#pragma unroll
    for (int r = 0; r < 4; ++r)
#pragma unroll
      for (int d = 1; d < 16; d <<= 1) lr[m][r] += __shfl_xor(lr[m][r], d, 16);
    ushort_t* op = Ob + (size_t)(b * 2048 + q0w + 16 * m) * 2048 + hq * 128;
#pragma unroll
    for (int ni = 0; ni < 8; ++ni)
#pragma unroll
      for (int r = 0; r < 4; ++r)
        op[(size_t)(l4 * 4 + r) * 2048 + ni * 16 + l15] = f2bf(o[m][ni][r] / lr[m][r]);
  }
}

// ---------------- launch ----------------
extern "C" void kernel_launch(void* const* d_in, const int* in_sizes, int n_in,
                              void* d_out, int out_size, void* d_ws, size_t ws_size,
                              hipStream_t stream) {
  const float* x  = (const float*)d_in[0];
  const float* Wq = (const float*)d_in[1];
  const float* Wk = (const float*)d_in[2];
  const float* Wv = (const float*)d_in[3];
  const float* Wp = (const float*)d_in[4];
  const float* bp = (const float*)d_in[5];
  float* out = (float*)d_out;

  char* ws = (char*)d_ws;
  size_t off = 0;
  ushort_t* xb    = (ushort_t*)(ws + off); off += (size_t)4096 * 2048 * 2;
  ushort_t* wqkb  = (ushort_t*)(ws + off); off += (size_t)2560 * 2048 * 2;  // [Wq; Wk_c]
  ushort_t* wvb   = (ushort_t*)(ws + off); off += (size_t)512 * 2048 * 2;
  ushort_t* wpb   = (ushort_t*)(ws + off); off += (size_t)2048 * 2048 * 2;
  ushort_t* qkbuf = (ushort_t*)(ws + off); off += (size_t)4096 * 2560 * 2;  // Q | K
  ushort_t* vtb   = (ushort_t*)(ws + off); off += (size_t)512 * 4096 * 2;
  ushort_t* obuf  = (ushort_t*)(ws + off); off += (size_t)4096 * 2048 * 2;

  cast4<<<8192, 256, 0, stream>>>(x, xb);                          // 4096x2048
  cast4<<<4096, 256, 0, stream>>>(Wq, wqkb);                       // rows 0..2047
  cast_compact<<<1024, 256, 0, stream>>>(Wk, wqkb + (size_t)2048 * 2048); // rows 2048..2559
  cast_compact<<<1024, 256, 0, stream>>>(Wv, wvb);
  cast4<<<4096, 256, 0, stream>>>(Wp, wpb);

  // [Q | K] = x [Wq; Wk_c]^T   (4096 x 2560)
  gemm_bt<false><<<dim3(20, 32), 256, 0, stream>>>(xb, wqkb, qkbuf, nullptr, nullptr,
                                                   4096, 2560, 2048);
  // V^T = Wv_c x^T             (512 x 4096)  -- swapped operands emit transposed V
  gemm_bt<false><<<dim3(32, 4), 256, 0, stream>>>(wvb, xb, vtb, nullptr, nullptr,
                                                  512, 4096, 2048);

  attn_kernel<<<512, 256, 0, stream>>>(qkbuf, 2560, qkbuf + 2048, 2560, vtb, obuf);

  // out = O Wp^T + bp          (4096 x 2048, f32)
  gemm_bt<true><<<dim3(16, 32), 256, 0, stream>>>(obuf, wpb, nullptr, out, bp,
                                                  4096, 2048, 2048);
}

// Round 5
// 376.066 us; speedup vs baseline: 2.1971x; 1.1842x over previous
//
#include <hip/hip_runtime.h>
#include <hip/hip_bf16.h>

// GQA: B=2, T=2048, EMB=2048, H=16, G=4, GS=4, HD=128, causal, eval-mode dropout.
// Pipeline: cast(bf16) -> fused QK projection + V^T projection -> flash attention
// (causal-paired q-tiles, dbuf LDS K/V, 1 barrier/iter, defer-max) -> out proj.

typedef unsigned short ushort_t;
typedef __bf16 bf16x8 __attribute__((ext_vector_type(8)));
typedef float f32x4 __attribute__((ext_vector_type(4)));

__device__ __forceinline__ ushort_t f2bf(float f) {
  union { float f; unsigned u; } x; x.f = f;
  unsigned r = x.u + 0x7fffu + ((x.u >> 16) & 1u);
  return (ushort_t)(r >> 16);
}

// ---------------- casts ----------------
__global__ __launch_bounds__(256) void cast4(const float* __restrict__ in,
                                             ushort_t* __restrict__ out) {
  int i = blockIdx.x * 256 + threadIdx.x;
  float4 v = reinterpret_cast<const float4*>(in)[i];
  ushort4 o;
  o.x = f2bf(v.x); o.y = f2bf(v.y); o.z = f2bf(v.z); o.w = f2bf(v.w);
  reinterpret_cast<ushort4*>(out)[i] = o;
}

// Wk/Wv: keep only rows g*512+d (d<128) -> compact 512x2048, row n = g*128+d.
__global__ __launch_bounds__(256) void cast_compact(const float* __restrict__ in,
                                                    ushort_t* __restrict__ out) {
  int i = blockIdx.x * 256 + threadIdx.x;   // 512 rows * 512 float4 chunks
  int row = i >> 9, c = i & 511;
  int srow = ((row >> 7) << 9) | (row & 127);
  float4 v = reinterpret_cast<const float4*>(in + (size_t)srow * 2048)[c];
  ushort4 o;
  o.x = f2bf(v.x); o.y = f2bf(v.y); o.z = f2bf(v.z); o.w = f2bf(v.w);
  reinterpret_cast<ushort4*>(out + (size_t)row * 2048)[c] = o;
}

// ---------------- GEMM: C[M,N] = A[M,K] * B[N,K]^T (both row-major, K-contig) ----
template<bool FINAL>
__global__ __launch_bounds__(256) void gemm_bt(const ushort_t* __restrict__ A,
                                               const ushort_t* __restrict__ B,
                                               ushort_t* __restrict__ Cb,
                                               float* __restrict__ Cf,
                                               const float* __restrict__ bias,
                                               int M, int N, int K) {
  __shared__ ushort_t lA[128 * 32];
  __shared__ ushort_t lB[128 * 32];
  const int lane = threadIdx.x & 63;
  const int w = threadIdx.x >> 6;
  const int m0 = blockIdx.y * 128;
  const int n0 = blockIdx.x * 128;
  const int wm = (w >> 1) * 64, wn = (w & 1) * 64;
  const int l4 = lane >> 4, l15 = lane & 15;

  const f32x4 zero = {0.f, 0.f, 0.f, 0.f};
  f32x4 acc[4][4];
#pragma unroll
  for (int i = 0; i < 4; ++i)
#pragma unroll
    for (int j = 0; j < 4; ++j) acc[i][j] = zero;

  const int srow = w * 16 + (lane >> 2);
  const int scol = (lane & 3) * 8;
  const ushort_t* ga = A + (size_t)(m0 + srow) * K + scol;
  const ushort_t* gb = B + (size_t)(n0 + srow) * K + scol;

  for (int kt = 0; kt < K; kt += 32) {
#pragma unroll
    for (int i = 0; i < 2; ++i) {
      __builtin_amdgcn_global_load_lds(
          (const __attribute__((address_space(1))) void*)(ga + (size_t)i * 64 * K + kt),
          (__attribute__((address_space(3))) void*)(&lA[w * 512 + i * 2048]), 16, 0, 0);
      __builtin_amdgcn_global_load_lds(
          (const __attribute__((address_space(1))) void*)(gb + (size_t)i * 64 * K + kt),
          (__attribute__((address_space(3))) void*)(&lB[w * 512 + i * 2048]), 16, 0, 0);
    }
    __syncthreads();
    bf16x8 af[4], bfr[4];
#pragma unroll
    for (int t = 0; t < 4; ++t) {
      af[t]  = *reinterpret_cast<const bf16x8*>(&lA[(wm + t * 16 + l15) * 32 + l4 * 8]);
      bfr[t] = *reinterpret_cast<const bf16x8*>(&lB[(wn + t * 16 + l15) * 32 + l4 * 8]);
    }
#pragma unroll
    for (int mi = 0; mi < 4; ++mi)
#pragma unroll
      for (int ni = 0; ni < 4; ++ni)
        acc[mi][ni] = __builtin_amdgcn_mfma_f32_16x16x32_bf16(af[mi], bfr[ni],
                                                              acc[mi][ni], 0, 0, 0);
    __syncthreads();
  }

#pragma unroll
  for (int mi = 0; mi < 4; ++mi)
#pragma unroll
    for (int ni = 0; ni < 4; ++ni) {
      int row = m0 + wm + mi * 16 + l4 * 4;
      int col = n0 + wn + ni * 16 + l15;
#pragma unroll
      for (int r = 0; r < 4; ++r) {
        float v = acc[mi][ni][r];
        if (FINAL) Cf[(size_t)(row + r) * N + col] = v + bias[col];
        else       Cb[(size_t)(row + r) * N + col] = f2bf(v);
      }
    }
}

// ---------------- flash attention v3 ----------------
// Block = 4 waves x 16 q-rows, handles causal PAIR of 64-row q-tiles (tau, 31-tau)
// sequentially -> uniform 33 KV-iters/block. K/V double-buffered in LDS
// (XOR-swizzled), STAGE(t+1) issued before compute(t), ONE barrier per iter.
// Q pre-scaled by sc*log2(e); defer-max (THR=8) skips rescale on interior tiles.
__global__ __launch_bounds__(256, 2) void attn_kernel(const ushort_t* __restrict__ Qb, int ldQ,
                                                      const ushort_t* __restrict__ Kb, int ldK,
                                                      const ushort_t* __restrict__ Vt,
                                                      ushort_t* __restrict__ Ob) {
  __shared__ ushort_t ldsK[2][64 * 128];   // row r: chunk c (16B) at slot c^(r&7)
  __shared__ ushort_t ldsV[2][128 * 64];   // row d: chunk c at slot c^(d&7)
  __shared__ ushort_t pbuf[4][16 * 72];    // per-wave P tile (no barrier needed)

  const int lane = threadIdx.x & 63;
  const int w = threadIdx.x >> 6;
  const int swz = ((blockIdx.x & 7) << 6) | (blockIdx.x >> 3);  // chunked XCD swizzle
  const int b = swz >> 8, hq = (swz >> 4) & 15, pair = swz & 15;
  const int g = hq >> 2;
  const int l4 = lane >> 4, l15 = lane & 15;
  const int tau_hi = 31 - pair, tau_lo = pair;
  const int hi_iters = tau_hi + 1;          // 17..32
  const int total_iters = hi_iters + tau_lo + 1;  // == 33 for all blocks
  const float C = 0.12751744f;              // (1/sqrt(128)) * log2(e)

  // staging base pointers (row&7 invariant across issues)
  const int krow = w * 4 + (lane >> 4);
  const ushort_t* kBase = Kb + (size_t)(b * 2048 + krow) * ldK + g * 128 + ((lane & 15) ^ (krow & 7)) * 8;
  const int vrow = w * 8 + (lane >> 3);
  const ushort_t* vBase = Vt + (size_t)(g * 128 + vrow) * 4096 + b * 2048 + ((lane & 7) ^ (vrow & 7)) * 8;

  const f32x4 zero = {0.f, 0.f, 0.f, 0.f};
  f32x4 o[8];
  float mr[4], lr[4];
  bf16x8 qf[4];

  auto LOADQ = [&](int tau) {
    const ushort_t* qp = Qb + (size_t)(b * 2048 + tau * 64 + w * 16 + l15) * ldQ + hq * 128 + l4 * 8;
#pragma unroll
    for (int kk = 0; kk < 4; ++kk) {
      bf16x8 q = *reinterpret_cast<const bf16x8*>(qp + kk * 32);
#pragma unroll
      for (int j = 0; j < 8; ++j) q[j] = (__bf16)((float)q[j] * C);  // fold scale+log2e
      qf[kk] = q;
    }
  };
  auto RESET = [&]() {
#pragma unroll
    for (int i = 0; i < 8; ++i) o[i] = zero;
#pragma unroll
    for (int r = 0; r < 4; ++r) { mr[r] = -3.0e38f; lr[r] = 0.f; }
  };
  auto STAGE = [&](int tt, int bc) {
    const int js = (tt < hi_iters) ? tt * 64 : (tt - hi_iters) * 64;
    const ushort_t* ks = kBase + (size_t)js * ldK;
    const ushort_t* vs = vBase + js;
#pragma unroll
    for (int i = 0; i < 4; ++i) {
      __builtin_amdgcn_global_load_lds(
          (const __attribute__((address_space(1))) void*)(ks + (size_t)i * 16 * ldK),
          (__attribute__((address_space(3))) void*)(&ldsK[bc][i * 2048 + w * 512]), 16, 0, 0);
      __builtin_amdgcn_global_load_lds(
          (const __attribute__((address_space(1))) void*)(vs + (size_t)i * 32 * 4096),
          (__attribute__((address_space(3))) void*)(&ldsV[bc][i * 2048 + w * 512]), 16, 0, 0);
    }
  };
  auto FINALIZE = [&](int tau) {
#pragma unroll
    for (int r = 0; r < 4; ++r) {
#pragma unroll
      for (int d = 1; d < 16; d <<= 1) lr[r] += __shfl_xor(lr[r], d, 16);
      lr[r] = 1.0f / lr[r];
    }
    ushort_t* op = Ob + (size_t)(b * 2048 + tau * 64 + w * 16) * 2048 + hq * 128;
#pragma unroll
    for (int ni = 0; ni < 8; ++ni)
#pragma unroll
      for (int r = 0; r < 4; ++r)
        op[(size_t)(l4 * 4 + r) * 2048 + ni * 16 + l15] = f2bf(o[ni][r] * lr[r]);
  };

  RESET();
  LOADQ(tau_hi);
  STAGE(0, 0);

  for (int t = 0; t < total_iters; ++t) {
    if (t == hi_iters) {        // phase switch: finish hi tile, start lo tile
      FINALIZE(tau_hi);
      RESET();
      LOADQ(tau_lo);
    }
    __syncthreads();            // drains vmcnt: buf[t&1] tiles ready; buf[(t+1)&1] free
    if (t + 1 < total_iters) STAGE(t + 1, (t + 1) & 1);
    const int bc = t & 1;

    const int tau = (t < hi_iters) ? tau_hi : tau_lo;
    const int tloc = (t < hi_iters) ? t : (t - hi_iters);
    const int j0 = tloc * 64;
    const int q0 = tau * 64 + w * 16;
    const bool diag = (tloc == tau);   // only last iter of a phase needs masking

    // ---- S = Q K^T (16 x 64), S already in log2-softmax units ----
    f32x4 s[4];
#pragma unroll
    for (int i = 0; i < 4; ++i) s[i] = zero;
#pragma unroll
    for (int ni = 0; ni < 4; ++ni) {
      const int R = ni * 16 + l15;
#pragma unroll
      for (int kk = 0; kk < 4; ++kk) {
        bf16x8 kf = *reinterpret_cast<const bf16x8*>(
            &ldsK[bc][R * 128 + ((kk * 4 + l4) ^ (R & 7)) * 8]);
        s[ni] = __builtin_amdgcn_mfma_f32_16x16x32_bf16(qf[kk], kf, s[ni], 0, 0, 0);
      }
    }
    // ---- mask (diag only) + per-lane max ----
    float pmax[4] = {-3.0e38f, -3.0e38f, -3.0e38f, -3.0e38f};
    if (diag) {
#pragma unroll
      for (int ni = 0; ni < 4; ++ni) {
        int col = j0 + ni * 16 + l15;
#pragma unroll
        for (int r = 0; r < 4; ++r) {
          int qq = q0 + l4 * 4 + r;
          float v = (col <= qq) ? s[ni][r] : -3.0e38f;
          s[ni][r] = v;
          pmax[r] = fmaxf(pmax[r], v);
        }
      }
    } else {
#pragma unroll
      for (int ni = 0; ni < 4; ++ni)
#pragma unroll
        for (int r = 0; r < 4; ++r) pmax[r] = fmaxf(pmax[r], s[ni][r]);
    }
    // ---- defer-max: only rescale when some row max grew past THR=8 ----
    bool small = (pmax[0] <= mr[0] + 8.f) & (pmax[1] <= mr[1] + 8.f) &
                 (pmax[2] <= mr[2] + 8.f) & (pmax[3] <= mr[3] + 8.f);
    if (!__all(small)) {
#pragma unroll
      for (int r = 0; r < 4; ++r) {
#pragma unroll
        for (int d = 1; d < 16; d <<= 1) pmax[r] = fmaxf(pmax[r], __shfl_xor(pmax[r], d, 16));
        float mn = fmaxf(mr[r], pmax[r]);
        float corr = exp2f(mr[r] - mn);
        mr[r] = mn;
        lr[r] *= corr;
#pragma unroll
        for (int i = 0; i < 8; ++i) o[i][r] *= corr;
      }
    }
    // ---- P = exp2(S - m), row-sum, stash to per-wave LDS for A-frag reshape ----
#pragma unroll
    for (int ni = 0; ni < 4; ++ni)
#pragma unroll
      for (int r = 0; r < 4; ++r) {
        float p = exp2f(s[ni][r] - mr[r]);
        lr[r] += p;
        pbuf[w][(l4 * 4 + r) * 72 + ni * 16 + l15] = f2bf(p);
      }
    bf16x8 pa[2];
#pragma unroll
    for (int kk2 = 0; kk2 < 2; ++kk2)
      pa[kk2] = *reinterpret_cast<const bf16x8*>(&pbuf[w][l15 * 72 + kk2 * 32 + l4 * 8]);
    // ---- O += P V ----
#pragma unroll
    for (int ni = 0; ni < 8; ++ni) {
      const int R = ni * 16 + l15;
#pragma unroll
      for (int kk2 = 0; kk2 < 2; ++kk2) {
        bf16x8 vf = *reinterpret_cast<const bf16x8*>(
            &ldsV[bc][R * 64 + ((kk2 * 4 + l4) ^ (R & 7)) * 8]);
        o[ni] = __builtin_amdgcn_mfma_f32_16x16x32_bf16(pa[kk2], vf, o[ni], 0, 0, 0);
      }
    }
  }
  FINALIZE(tau_lo);
}

// ---------------- launch ----------------
extern "C" void kernel_launch(void* const* d_in, const int* in_sizes, int n_in,
                              void* d_out, int out_size, void* d_ws, size_t ws_size,
                              hipStream_t stream) {
  const float* x  = (const float*)d_in[0];
  const float* Wq = (const float*)d_in[1];
  const float* Wk = (const float*)d_in[2];
  const float* Wv = (const float*)d_in[3];
  const float* Wp = (const float*)d_in[4];
  const float* bp = (const float*)d_in[5];
  float* out = (float*)d_out;

  char* ws = (char*)d_ws;
  size_t off = 0;
  ushort_t* xb    = (ushort_t*)(ws + off); off += (size_t)4096 * 2048 * 2;
  ushort_t* wqkb  = (ushort_t*)(ws + off); off += (size_t)2560 * 2048 * 2;  // [Wq; Wk_c]
  ushort_t* wvb   = (ushort_t*)(ws + off); off += (size_t)512 * 2048 * 2;
  ushort_t* wpb   = (ushort_t*)(ws + off); off += (size_t)2048 * 2048 * 2;
  ushort_t* qkbuf = (ushort_t*)(ws + off); off += (size_t)4096 * 2560 * 2;  // Q | K
  ushort_t* vtb   = (ushort_t*)(ws + off); off += (size_t)512 * 4096 * 2;
  ushort_t* obuf  = (ushort_t*)(ws + off); off += (size_t)4096 * 2048 * 2;

  cast4<<<8192, 256, 0, stream>>>(x, xb);
  cast4<<<4096, 256, 0, stream>>>(Wq, wqkb);
  cast_compact<<<1024, 256, 0, stream>>>(Wk, wqkb + (size_t)2048 * 2048);
  cast_compact<<<1024, 256, 0, stream>>>(Wv, wvb);
  cast4<<<4096, 256, 0, stream>>>(Wp, wpb);

  // [Q | K] = x [Wq; Wk_c]^T   (4096 x 2560)
  gemm_bt<false><<<dim3(20, 32), 256, 0, stream>>>(xb, wqkb, qkbuf, nullptr, nullptr,
                                                   4096, 2560, 2048);
  // V^T = Wv_c x^T             (512 x 4096)
  gemm_bt<false><<<dim3(32, 4), 256, 0, stream>>>(wvb, xb, vtb, nullptr, nullptr,
                                                  512, 4096, 2048);

  attn_kernel<<<512, 256, 0, stream>>>(qkbuf, 2560, qkbuf + 2048, 2560, vtb, obuf);

  // out = O Wp^T + bp          (4096 x 2048, f32)
  gemm_bt<true><<<dim3(16, 32), 256, 0, stream>>>(obuf, wpb, nullptr, out, bp,
                                                  4096, 2048, 2048);
}

// Round 6
// 307.259 us; speedup vs baseline: 2.6892x; 1.2239x over previous
//
#include <hip/hip_runtime.h>
#include <hip/hip_bf16.h>

// GQA: B=2, T=2048, EMB=2048, H=16, G=4, GS=4, HD=128, causal, eval-mode dropout.
// 4 dispatches: cast_all -> proj_fused ([Q|K] + V^T) -> attention -> out proj.
// GEMM core: 128x128 tile, BK=64, XOR-swizzled LDS (conflict-free ds_read_b128).

typedef unsigned short ushort_t;
typedef __bf16 bf16x8 __attribute__((ext_vector_type(8)));
typedef float f32x4 __attribute__((ext_vector_type(4)));

__device__ __forceinline__ ushort_t f2bf(float f) {
  union { float f; unsigned u; } x; x.f = f;
  unsigned r = x.u + 0x7fffu + ((x.u >> 16) & 1u);
  return (ushort_t)(r >> 16);
}

// ---------------- fused casts (5 logical casts, 1 dispatch) ----------------
__device__ __forceinline__ void cast_plain(const float* __restrict__ in,
                                           ushort_t* __restrict__ out, int i) {
  float4 v = reinterpret_cast<const float4*>(in)[i];
  ushort4 o;
  o.x = f2bf(v.x); o.y = f2bf(v.y); o.z = f2bf(v.z); o.w = f2bf(v.w);
  reinterpret_cast<ushort4*>(out)[i] = o;
}
// keep only rows g*512+d (d<128) -> compact 512x2048, row n = g*128+d
__device__ __forceinline__ void cast_cmp(const float* __restrict__ in,
                                         ushort_t* __restrict__ out, int i) {
  int row = i >> 9, c = i & 511;
  int srow = ((row >> 7) << 9) | (row & 127);
  float4 v = reinterpret_cast<const float4*>(in + (size_t)srow * 2048)[c];
  ushort4 o;
  o.x = f2bf(v.x); o.y = f2bf(v.y); o.z = f2bf(v.z); o.w = f2bf(v.w);
  reinterpret_cast<ushort4*>(out + (size_t)row * 2048)[c] = o;
}
__global__ __launch_bounds__(256) void cast_all(const float* __restrict__ x,
                                                const float* __restrict__ Wq,
                                                const float* __restrict__ Wk,
                                                const float* __restrict__ Wv,
                                                const float* __restrict__ Wp,
                                                ushort_t* __restrict__ xb,
                                                ushort_t* __restrict__ wqkb,
                                                ushort_t* __restrict__ wvb,
                                                ushort_t* __restrict__ wpb) {
  int bid = blockIdx.x, tid = threadIdx.x;
  if (bid < 8192)       cast_plain(x,  xb,  bid * 256 + tid);
  else if (bid < 12288) cast_plain(Wq, wqkb, (bid - 8192) * 256 + tid);
  else if (bid < 16384) cast_plain(Wp, wpb, (bid - 12288) * 256 + tid);
  else if (bid < 17408) cast_cmp(Wk, wqkb + (size_t)2048 * 2048, (bid - 16384) * 256 + tid);
  else                  cast_cmp(Wv, wvb, (bid - 17408) * 256 + tid);
}

// ---------------- GEMM tile: C[M,N] = A[M,K] * B[N,K]^T ----------------
// 128x128 tile, BK=64, 4 waves (2x2 of 64x64). LDS row r stores 16B-chunk c at
// slot c^(r&7): staged via pre-swizzled global source (linear gload_lds dest),
// read back with the same XOR -> conflict-free ds_read_b128 (rule-21 pattern).
template<bool FINAL>
__device__ __forceinline__ void gemm_tile(ushort_t* __restrict__ lA,   // [128*64]
                                          ushort_t* __restrict__ lB,   // [128*64]
                                          const ushort_t* __restrict__ A,
                                          const ushort_t* __restrict__ B,
                                          ushort_t* __restrict__ Cb,
                                          float* __restrict__ Cf,
                                          const float* __restrict__ bias,
                                          int m0, int n0, int N, int K) {
  const int lane = threadIdx.x & 63;
  const int w = threadIdx.x >> 6;
  const int wm = (w >> 1) * 64, wn = (w & 1) * 64;
  const int l4 = lane >> 4, l15 = lane & 15;

  const f32x4 zero = {0.f, 0.f, 0.f, 0.f};
  f32x4 acc[4][4];
#pragma unroll
  for (int i = 0; i < 4; ++i)
#pragma unroll
    for (int j = 0; j < 4; ++j) acc[i][j] = zero;

  // staging: issue i covers rows i*32 + w*8 + (lane>>3); lane reads the global
  // 16B chunk that belongs at its linear LDS slot: c = (lane&7) ^ (row&7).
  const int srow = w * 8 + (lane >> 3);                    // row&7 == lane>>3
  const int scol = ((lane & 7) ^ (lane >> 3)) * 8;
  const ushort_t* ga = A + (size_t)(m0 + srow) * K + scol;
  const ushort_t* gb = B + (size_t)(n0 + srow) * K + scol;

  for (int kt = 0; kt < K; kt += 64) {
#pragma unroll
    for (int i = 0; i < 4; ++i) {
      __builtin_amdgcn_global_load_lds(
          (const __attribute__((address_space(1))) void*)(ga + (size_t)i * 32 * K + kt),
          (__attribute__((address_space(3))) void*)(&lA[i * 2048 + w * 512]), 16, 0, 0);
      __builtin_amdgcn_global_load_lds(
          (const __attribute__((address_space(1))) void*)(gb + (size_t)i * 32 * K + kt),
          (__attribute__((address_space(3))) void*)(&lB[i * 2048 + w * 512]), 16, 0, 0);
    }
    __syncthreads();  // drains vmcnt + barrier
#pragma unroll
    for (int kk = 0; kk < 2; ++kk) {
      bf16x8 af[4], bfr[4];
#pragma unroll
      for (int t = 0; t < 4; ++t) {
        const int Ra = wm + t * 16 + l15;
        const int Rb = wn + t * 16 + l15;
        af[t]  = *reinterpret_cast<const bf16x8*>(&lA[Ra * 64 + ((kk * 4 + l4) ^ (Ra & 7)) * 8]);
        bfr[t] = *reinterpret_cast<const bf16x8*>(&lB[Rb * 64 + ((kk * 4 + l4) ^ (Rb & 7)) * 8]);
      }
#pragma unroll
      for (int mi = 0; mi < 4; ++mi)
#pragma unroll
        for (int ni = 0; ni < 4; ++ni)
          acc[mi][ni] = __builtin_amdgcn_mfma_f32_16x16x32_bf16(af[mi], bfr[ni],
                                                                acc[mi][ni], 0, 0, 0);
    }
    __syncthreads();
  }

#pragma unroll
  for (int mi = 0; mi < 4; ++mi)
#pragma unroll
    for (int ni = 0; ni < 4; ++ni) {
      int row = m0 + wm + mi * 16 + l4 * 4;
      int col = n0 + wn + ni * 16 + l15;
#pragma unroll
      for (int r = 0; r < 4; ++r) {
        float v = acc[mi][ni][r];
        if (FINAL) Cf[(size_t)(row + r) * N + col] = v + bias[col];
        else       Cb[(size_t)(row + r) * N + col] = f2bf(v);
      }
    }
}

// one dispatch: blocks 0..639 -> [Q|K] = x [Wq;Wk_c]^T (4096x2560);
//               blocks 640..767 -> V^T = Wv_c x^T (512x4096)
__global__ __launch_bounds__(256) void proj_fused(const ushort_t* __restrict__ xb,
                                                  const ushort_t* __restrict__ wqkb,
                                                  const ushort_t* __restrict__ wvb,
                                                  ushort_t* __restrict__ qkbuf,
                                                  ushort_t* __restrict__ vtb) {
  __shared__ ushort_t lA[128 * 64];
  __shared__ ushort_t lB[128 * 64];
  int bid = blockIdx.x;
  if (bid < 640) {
    gemm_tile<false>(lA, lB, xb, wqkb, qkbuf, nullptr, nullptr,
                     (bid / 20) * 128, (bid % 20) * 128, 2560, 2048);
  } else {
    int t = bid - 640;
    gemm_tile<false>(lA, lB, wvb, xb, vtb, nullptr, nullptr,
                     (t / 32) * 128, (t % 32) * 128, 4096, 2048);
  }
}

__global__ __launch_bounds__(256) void gemm_final(const ushort_t* __restrict__ A,
                                                  const ushort_t* __restrict__ B,
                                                  float* __restrict__ Cf,
                                                  const float* __restrict__ bias) {
  __shared__ ushort_t lA[128 * 64];
  __shared__ ushort_t lB[128 * 64];
  gemm_tile<true>(lA, lB, A, B, nullptr, Cf, bias,
                  (int)blockIdx.y * 128, (int)blockIdx.x * 128, 2048, 2048);
}

// ---------------- flash attention v3 (unchanged from round 5) ----------------
__global__ __launch_bounds__(256, 2) void attn_kernel(const ushort_t* __restrict__ Qb, int ldQ,
                                                      const ushort_t* __restrict__ Kb, int ldK,
                                                      const ushort_t* __restrict__ Vt,
                                                      ushort_t* __restrict__ Ob) {
  __shared__ ushort_t ldsK[2][64 * 128];   // row r: chunk c (16B) at slot c^(r&7)
  __shared__ ushort_t ldsV[2][128 * 64];   // row d: chunk c at slot c^(d&7)
  __shared__ ushort_t pbuf[4][16 * 72];    // per-wave P tile (no barrier needed)

  const int lane = threadIdx.x & 63;
  const int w = threadIdx.x >> 6;
  const int swz = ((blockIdx.x & 7) << 6) | (blockIdx.x >> 3);  // chunked XCD swizzle
  const int b = swz >> 8, hq = (swz >> 4) & 15, pair = swz & 15;
  const int g = hq >> 2;
  const int l4 = lane >> 4, l15 = lane & 15;
  const int tau_hi = 31 - pair, tau_lo = pair;
  const int hi_iters = tau_hi + 1;
  const int total_iters = hi_iters + tau_lo + 1;  // == 33 for all blocks
  const float C = 0.12751744f;              // (1/sqrt(128)) * log2(e)

  const int krow = w * 4 + (lane >> 4);
  const ushort_t* kBase = Kb + (size_t)(b * 2048 + krow) * ldK + g * 128 + ((lane & 15) ^ (krow & 7)) * 8;
  const int vrow = w * 8 + (lane >> 3);
  const ushort_t* vBase = Vt + (size_t)(g * 128 + vrow) * 4096 + b * 2048 + ((lane & 7) ^ (vrow & 7)) * 8;

  const f32x4 zero = {0.f, 0.f, 0.f, 0.f};
  f32x4 o[8];
  float mr[4], lr[4];
  bf16x8 qf[4];

  auto LOADQ = [&](int tau) {
    const ushort_t* qp = Qb + (size_t)(b * 2048 + tau * 64 + w * 16 + l15) * ldQ + hq * 128 + l4 * 8;
#pragma unroll
    for (int kk = 0; kk < 4; ++kk) {
      bf16x8 q = *reinterpret_cast<const bf16x8*>(qp + kk * 32);
#pragma unroll
      for (int j = 0; j < 8; ++j) q[j] = (__bf16)((float)q[j] * C);
      qf[kk] = q;
    }
  };
  auto RESET = [&]() {
#pragma unroll
    for (int i = 0; i < 8; ++i) o[i] = zero;
#pragma unroll
    for (int r = 0; r < 4; ++r) { mr[r] = -3.0e38f; lr[r] = 0.f; }
  };
  auto STAGE = [&](int tt, int bc) {
    const int js = (tt < hi_iters) ? tt * 64 : (tt - hi_iters) * 64;
    const ushort_t* ks = kBase + (size_t)js * ldK;
    const ushort_t* vs = vBase + js;
#pragma unroll
    for (int i = 0; i < 4; ++i) {
      __builtin_amdgcn_global_load_lds(
          (const __attribute__((address_space(1))) void*)(ks + (size_t)i * 16 * ldK),
          (__attribute__((address_space(3))) void*)(&ldsK[bc][i * 2048 + w * 512]), 16, 0, 0);
      __builtin_amdgcn_global_load_lds(
          (const __attribute__((address_space(1))) void*)(vs + (size_t)i * 32 * 4096),
          (__attribute__((address_space(3))) void*)(&ldsV[bc][i * 2048 + w * 512]), 16, 0, 0);
    }
  };
  auto FINALIZE = [&](int tau) {
#pragma unroll
    for (int r = 0; r < 4; ++r) {
#pragma unroll
      for (int d = 1; d < 16; d <<= 1) lr[r] += __shfl_xor(lr[r], d, 16);
      lr[r] = 1.0f / lr[r];
    }
    ushort_t* op = Ob + (size_t)(b * 2048 + tau * 64 + w * 16) * 2048 + hq * 128;
#pragma unroll
    for (int ni = 0; ni < 8; ++ni)
#pragma unroll
      for (int r = 0; r < 4; ++r)
        op[(size_t)(l4 * 4 + r) * 2048 + ni * 16 + l15] = f2bf(o[ni][r] * lr[r]);
  };

  RESET();
  LOADQ(tau_hi);
  STAGE(0, 0);

  for (int t = 0; t < total_iters; ++t) {
    if (t == hi_iters) {
      FINALIZE(tau_hi);
      RESET();
      LOADQ(tau_lo);
    }
    __syncthreads();
    if (t + 1 < total_iters) STAGE(t + 1, (t + 1) & 1);
    const int bc = t & 1;

    const int tau = (t < hi_iters) ? tau_hi : tau_lo;
    const int tloc = (t < hi_iters) ? t : (t - hi_iters);
    const int j0 = tloc * 64;
    const int q0 = tau * 64 + w * 16;
    const bool diag = (tloc == tau);

    f32x4 s[4];
#pragma unroll
    for (int i = 0; i < 4; ++i) s[i] = zero;
#pragma unroll
    for (int ni = 0; ni < 4; ++ni) {
      const int R = ni * 16 + l15;
#pragma unroll
      for (int kk = 0; kk < 4; ++kk) {
        bf16x8 kf = *reinterpret_cast<const bf16x8*>(
            &ldsK[bc][R * 128 + ((kk * 4 + l4) ^ (R & 7)) * 8]);
        s[ni] = __builtin_amdgcn_mfma_f32_16x16x32_bf16(qf[kk], kf, s[ni], 0, 0, 0);
      }
    }
    float pmax[4] = {-3.0e38f, -3.0e38f, -3.0e38f, -3.0e38f};
    if (diag) {
#pragma unroll
      for (int ni = 0; ni < 4; ++ni) {
        int col = j0 + ni * 16 + l15;
#pragma unroll
        for (int r = 0; r < 4; ++r) {
          int qq = q0 + l4 * 4 + r;
          float v = (col <= qq) ? s[ni][r] : -3.0e38f;
          s[ni][r] = v;
          pmax[r] = fmaxf(pmax[r], v);
        }
      }
    } else {
#pragma unroll
      for (int ni = 0; ni < 4; ++ni)
#pragma unroll
        for (int r = 0; r < 4; ++r) pmax[r] = fmaxf(pmax[r], s[ni][r]);
    }
    bool small = (pmax[0] <= mr[0] + 8.f) & (pmax[1] <= mr[1] + 8.f) &
                 (pmax[2] <= mr[2] + 8.f) & (pmax[3] <= mr[3] + 8.f);
    if (!__all(small)) {
#pragma unroll
      for (int r = 0; r < 4; ++r) {
#pragma unroll
        for (int d = 1; d < 16; d <<= 1) pmax[r] = fmaxf(pmax[r], __shfl_xor(pmax[r], d, 16));
        float mn = fmaxf(mr[r], pmax[r]);
        float corr = exp2f(mr[r] - mn);
        mr[r] = mn;
        lr[r] *= corr;
#pragma unroll
        for (int i = 0; i < 8; ++i) o[i][r] *= corr;
      }
    }
#pragma unroll
    for (int ni = 0; ni < 4; ++ni)
#pragma unroll
      for (int r = 0; r < 4; ++r) {
        float p = exp2f(s[ni][r] - mr[r]);
        lr[r] += p;
        pbuf[w][(l4 * 4 + r) * 72 + ni * 16 + l15] = f2bf(p);
      }
    bf16x8 pa[2];
#pragma unroll
    for (int kk2 = 0; kk2 < 2; ++kk2)
      pa[kk2] = *reinterpret_cast<const bf16x8*>(&pbuf[w][l15 * 72 + kk2 * 32 + l4 * 8]);
#pragma unroll
    for (int ni = 0; ni < 8; ++ni) {
      const int R = ni * 16 + l15;
#pragma unroll
      for (int kk2 = 0; kk2 < 2; ++kk2) {
        bf16x8 vf = *reinterpret_cast<const bf16x8*>(
            &ldsV[bc][R * 64 + ((kk2 * 4 + l4) ^ (R & 7)) * 8]);
        o[ni] = __builtin_amdgcn_mfma_f32_16x16x32_bf16(pa[kk2], vf, o[ni], 0, 0, 0);
      }
    }
  }
  FINALIZE(tau_lo);
}

// ---------------- launch ----------------
extern "C" void kernel_launch(void* const* d_in, const int* in_sizes, int n_in,
                              void* d_out, int out_size, void* d_ws, size_t ws_size,
                              hipStream_t stream) {
  const float* x  = (const float*)d_in[0];
  const float* Wq = (const float*)d_in[1];
  const float* Wk = (const float*)d_in[2];
  const float* Wv = (const float*)d_in[3];
  const float* Wp = (const float*)d_in[4];
  const float* bp = (const float*)d_in[5];
  float* out = (float*)d_out;

  char* ws = (char*)d_ws;
  size_t off = 0;
  ushort_t* xb    = (ushort_t*)(ws + off); off += (size_t)4096 * 2048 * 2;
  ushort_t* wqkb  = (ushort_t*)(ws + off); off += (size_t)2560 * 2048 * 2;  // [Wq; Wk_c]
  ushort_t* wvb   = (ushort_t*)(ws + off); off += (size_t)512 * 2048 * 2;
  ushort_t* wpb   = (ushort_t*)(ws + off); off += (size_t)2048 * 2048 * 2;
  ushort_t* qkbuf = (ushort_t*)(ws + off); off += (size_t)4096 * 2560 * 2;  // Q | K
  ushort_t* vtb   = (ushort_t*)(ws + off); off += (size_t)512 * 4096 * 2;
  ushort_t* obuf  = (ushort_t*)(ws + off); off += (size_t)4096 * 2048 * 2;

  cast_all<<<18432, 256, 0, stream>>>(x, Wq, Wk, Wv, Wp, xb, wqkb, wvb, wpb);

  proj_fused<<<768, 256, 0, stream>>>(xb, wqkb, wvb, qkbuf, vtb);

  attn_kernel<<<512, 256, 0, stream>>>(qkbuf, 2560, qkbuf + 2048, 2560, vtb, obuf);

  gemm_final<<<dim3(16, 32), 256, 0, stream>>>(obuf, wpb, out, bp);
}